// Round 1
// baseline (569.566 us; speedup 1.0000x reference)
//
#include <hip/hip_runtime.h>
#include <stdint.h>

typedef __bf16 bf16;
typedef __bf16 bf16x8 __attribute__((ext_vector_type(8)));
typedef float f32x4 __attribute__((ext_vector_type(4)));

enum { EPI_STORE = 0, EPI_BIAS_RELU = 1, EPI_VRED = 2 };

// C[M,N] = A[M,K] @ B[K,N], with B supplied transposed (Bt[N,K]).
// Tile: BM=128 x BN=256 x BK=32, 256 threads = 4 waves, wave tile 64x128.
// fp32 operands are converted to bf16 in-register during LDS staging.
// EPI_VRED: instead of storing C, computes per-block partial
//   v[col] = sum_rows adj_row0[row] * relu(C[row][col] + bias[col])
template<bool A_F32, bool B_F32, int EPI>
__global__ __launch_bounds__(256, 2)
void gemm_bt(const void* __restrict__ Ap, const void* __restrict__ Btp,
             const float* __restrict__ bias, bf16* __restrict__ C,
             float* __restrict__ vpart, const float* __restrict__ adjp,
             int K, int ldA, int ldBt, int ldC,
             long sA, long sBt, long sC)
{
  constexpr int BM = 128, BN = 256, BK = 32;
  __shared__ __align__(16) bf16 As[BM * BK];   // [m][k], 8 KB
  __shared__ __align__(16) bf16 Bs[BN * BK];   // [n][k], 16 KB
  __shared__ float a0s[BM];
  __shared__ float vsum[BN];

  const int tid  = threadIdx.x;
  const int lane = tid & 63;
  const int wid  = tid >> 6;
  const int wm   = wid >> 1;   // 0..1 : m half (64 rows)
  const int wn   = wid & 1;    // 0..1 : n half (128 cols)
  const int l15  = lane & 15;
  const int quad = lane >> 4;

  const int nb = blockIdx.x, mb = blockIdx.y, g = blockIdx.z;

  const long aoff = (long)g * sA + (long)mb * BM * ldA;
  const long boff = (long)g * sBt + (long)nb * BN * ldBt;

  if constexpr (EPI == EPI_VRED) {
    if (tid < BM) a0s[tid] = adjp[(long)g * sA + mb * BM + tid];  // adj[g][0][row]
    vsum[tid] = 0.f;
  }

  f32x4 acc[4][8] = {};

  const int nsteps = K / BK;
  const int r  = tid >> 2;          // staging row within 64-row pass
  const int kc = (tid & 3) * 8;     // staging k-chunk (8 elements)

  for (int ks = 0; ks < nsteps; ++ks) {
    const int k0 = ks * BK;
    __syncthreads();
    // ---- stage A tile (BM x BK) ----
    if constexpr (A_F32) {
      const float* Ag = (const float*)Ap + aoff + k0;
      #pragma unroll
      for (int p = 0; p < BM / 64; ++p) {
        const float4* s = (const float4*)(Ag + (long)(p * 64 + r) * ldA + kc);
        float4 v0 = s[0], v1 = s[1];
        bf16x8 w;
        w[0]=(bf16)v0.x; w[1]=(bf16)v0.y; w[2]=(bf16)v0.z; w[3]=(bf16)v0.w;
        w[4]=(bf16)v1.x; w[5]=(bf16)v1.y; w[6]=(bf16)v1.z; w[7]=(bf16)v1.w;
        *(bf16x8*)&As[p * 2048 + tid * 8] = w;
      }
    } else {
      const bf16* Ag = (const bf16*)Ap + aoff + k0;
      #pragma unroll
      for (int p = 0; p < BM / 64; ++p)
        *(bf16x8*)&As[p * 2048 + tid * 8] =
            *(const bf16x8*)(Ag + (long)(p * 64 + r) * ldA + kc);
    }
    // ---- stage Bt tile (BN x BK) ----
    if constexpr (B_F32) {
      const float* Bg = (const float*)Btp + boff + k0;
      #pragma unroll
      for (int p = 0; p < BN / 64; ++p) {
        const float4* s = (const float4*)(Bg + (long)(p * 64 + r) * ldBt + kc);
        float4 v0 = s[0], v1 = s[1];
        bf16x8 w;
        w[0]=(bf16)v0.x; w[1]=(bf16)v0.y; w[2]=(bf16)v0.z; w[3]=(bf16)v0.w;
        w[4]=(bf16)v1.x; w[5]=(bf16)v1.y; w[6]=(bf16)v1.z; w[7]=(bf16)v1.w;
        *(bf16x8*)&Bs[p * 2048 + tid * 8] = w;
      }
    } else {
      const bf16* Bg = (const bf16*)Btp + boff + k0;
      #pragma unroll
      for (int p = 0; p < BN / 64; ++p)
        *(bf16x8*)&Bs[p * 2048 + tid * 8] =
            *(const bf16x8*)(Bg + (long)(p * 64 + r) * ldBt + kc);
    }
    __syncthreads();

    // ---- fragments + MFMA ----
    bf16x8 af[4], bfr[8];
    #pragma unroll
    for (int i = 0; i < 4; ++i)
      af[i] = *(const bf16x8*)&As[(wm * 64 + i * 16 + l15) * BK + quad * 8];
    #pragma unroll
    for (int j = 0; j < 8; ++j)
      bfr[j] = *(const bf16x8*)&Bs[(wn * 128 + j * 16 + l15) * BK + quad * 8];
    #pragma unroll
    for (int i = 0; i < 4; ++i)
      #pragma unroll
      for (int j = 0; j < 8; ++j)
        acc[i][j] = __builtin_amdgcn_mfma_f32_16x16x32_bf16(af[i], bfr[j], acc[i][j], 0, 0, 0);
  }

  if constexpr (EPI == EPI_STORE || EPI == EPI_BIAS_RELU) {
    bf16* Cg = C + (long)g * sC;
    #pragma unroll
    for (int i = 0; i < 4; ++i) {
      const int row0 = mb * BM + wm * 64 + i * 16 + quad * 4;
      #pragma unroll
      for (int j = 0; j < 8; ++j) {
        const int col = nb * BN + wn * 128 + j * 16 + l15;
        float bv = 0.f;
        if constexpr (EPI == EPI_BIAS_RELU) bv = bias[col];
        #pragma unroll
        for (int rr = 0; rr < 4; ++rr) {
          float v = acc[i][j][rr];
          if constexpr (EPI == EPI_BIAS_RELU) v = fmaxf(v + bv, 0.f);
          Cg[(long)(row0 + rr) * ldC + col] = (bf16)v;
        }
      }
    }
  } else {  // EPI_VRED: H2 never materialized
    __syncthreads();
    #pragma unroll
    for (int j = 0; j < 8; ++j) {
      const int col = wn * 128 + j * 16 + l15;
      const float bv = bias[col];
      float p = 0.f;
      #pragma unroll
      for (int i = 0; i < 4; ++i) {
        const int lr = wm * 64 + i * 16 + quad * 4;
        #pragma unroll
        for (int rr = 0; rr < 4; ++rr)
          p += fmaxf(acc[i][j][rr] + bv, 0.f) * a0s[lr + rr];
      }
      atomicAdd(&vsum[col], p);
    }
    __syncthreads();
    vpart[((long)g * 8 + mb) * 256 + tid] = vsum[tid];
  }
}

// Transpose + convert weights: W0t[h][k]=W0[k][h] (256x128), W1t[h][k]=W1[k][h] (256x256)
__global__ void prep_w(const float* __restrict__ W0, const float* __restrict__ W1,
                       bf16* __restrict__ W0t, bf16* __restrict__ W1t)
{
  const int idx = blockIdx.x * 256 + threadIdx.x;  // 0..65535
  if (idx < 256 * 128) {
    const int h = idx >> 7, k = idx & 127;
    W0t[idx] = (bf16)W0[k * 256 + h];
  }
  const int h = idx >> 8, k = idx & 255;
  W1t[idx] = (bf16)W1[k * 256 + h];
}

// Per graph: v = sum of 8 partials; h3 = relu(v@W2 + b2); out = h3@Wl + bl (all fp32)
__global__ void finish_k(const float* __restrict__ vpart, const float* __restrict__ W2,
                         const float* __restrict__ b2, const float* __restrict__ Wl,
                         const float* __restrict__ bl, float* __restrict__ out)
{
  const int b = blockIdx.x, t = threadIdx.x;
  __shared__ float v[256], h3[256];
  float s = 0.f;
  #pragma unroll
  for (int mb = 0; mb < 8; ++mb) s += vpart[((long)b * 8 + mb) * 256 + t];
  v[t] = s;
  __syncthreads();
  float z = b2[t];
  for (int k = 0; k < 256; ++k) z += v[k] * W2[k * 256 + t];
  h3[t] = fmaxf(z, 0.f);
  __syncthreads();
  if (t < 128) {
    float o = bl[t];
    for (int h = 0; h < 256; ++h) o += h3[h] * Wl[h * 128 + t];
    out[(long)b * 128 + t] = o;
  }
}

extern "C" void kernel_launch(void* const* d_in, const int* in_sizes, int n_in,
                              void* d_out, int out_size, void* d_ws, size_t ws_size,
                              hipStream_t stream) {
  const float* embs = (const float*)d_in[0];  // [64,1024,128]
  const float* adj  = (const float*)d_in[1];  // [64,1024,1024]
  const float* W0   = (const float*)d_in[2];  // [128,256]
  const float* b0   = (const float*)d_in[3];
  const float* W1   = (const float*)d_in[4];  // [256,256]
  const float* b1   = (const float*)d_in[5];
  const float* W2   = (const float*)d_in[6];  // [256,256]
  const float* b2   = (const float*)d_in[7];
  const float* Wl   = (const float*)d_in[8];  // [256,128]
  const float* bl   = (const float*)d_in[9];
  float* out = (float*)d_out;

  char* ws = (char*)d_ws;
  bf16*  Zt    = (bf16*)(ws);                 // [64][256][1024] bf16 (Z0t then Z1t)
  bf16*  Hb    = (bf16*)(ws + 33554432);      // [64][1024][256] bf16 (H1)
  bf16*  W0t   = (bf16*)(ws + 67108864);      // [256][128]
  bf16*  W1t   = (bf16*)(ws + 67174400);      // [256][256]
  float* vpart = (float*)(ws + 67305472);     // [64][8][256] f32

  prep_w<<<256, 256, 0, stream>>>(W0, W1, W0t, W1t);

  // Z0t[h,n] = sum_k W0t[h,k]*embs[n,k] : M=256,N=1024,K=128
  gemm_bt<false, true, EPI_STORE><<<dim3(4, 2, 64), 256, 0, stream>>>(
      W0t, embs, nullptr, Zt, nullptr, nullptr,
      128, 128, 128, 1024, 0L, 131072L, 262144L);

  // H1[n,h] = relu(sum_m adj[n,m]*Z0t[h,m] + b0[h]) : M=1024,N=256,K=1024
  gemm_bt<true, false, EPI_BIAS_RELU><<<dim3(1, 8, 64), 256, 0, stream>>>(
      adj, Zt, b0, Hb, nullptr, nullptr,
      1024, 1024, 1024, 256, 1048576L, 262144L, 262144L);

  // Z1t[h,n] = sum_k W1t[h,k]*H1[n,k] : M=256,N=1024,K=256
  gemm_bt<false, false, EPI_STORE><<<dim3(4, 2, 64), 256, 0, stream>>>(
      W1t, Hb, nullptr, Zt, nullptr, nullptr,
      256, 256, 256, 1024, 0L, 262144L, 262144L);

  // vpart[g,mb,h] = sum_{rows in mb} adj[g,0,row]*relu(adj@Z1t + b1)[row,h]
  gemm_bt<true, false, EPI_VRED><<<dim3(1, 8, 64), 256, 0, stream>>>(
      adj, Zt, b1, nullptr, vpart, adj,
      1024, 1024, 1024, 256, 1048576L, 262144L, 0L);

  finish_k<<<64, 256, 0, stream>>>(vpart, W2, b2, Wl, bl, out);
}